// Round 13
// baseline (270.279 us; speedup 1.0000x reference)
//
#include <hip/hip_runtime.h>

#define L_NODES 100000
#define NFEAT   256
#define JDIM    128

typedef __bf16 bf16x8 __attribute__((ext_vector_type(8)));
typedef __bf16 bf16x4 __attribute__((ext_vector_type(4)));
typedef float  floatx4 __attribute__((ext_vector_type(4)));

// ---------------------------------------------------------------------------
// Prep:
//   WtH [128][256]: WtH[n][k]  = bf16(W_h1[k][n])
//   WtG2[256][128]: n<128: Wg[k][n]   (U cols);  n>=128: Wg[128+k][n-128] (V cols)
//     rows 128.. of WtG2 double as WtGv[n][k]=Wg[128+k][n] for k_gfinal.
// ---------------------------------------------------------------------------
__global__ __launch_bounds__(256) void k_prep(
    const float* __restrict__ Wh, const float* __restrict__ Wg,
    __bf16* __restrict__ WtH, __bf16* __restrict__ WtG2)
{
    int i = blockIdx.x * 256 + threadIdx.x;   // 32768
    int n = i >> 8, k = i & 255;
    WtH[i] = (__bf16)Wh[k * JDIM + n];
    int n2 = i >> 7, k2 = i & 127;
    WtG2[i] = (n2 < 128) ? (__bf16)Wg[k2 * JDIM + n2]
                         : (__bf16)Wg[(128 + k2) * JDIM + (n2 - 128)];
}

// ---------------------------------------------------------------------------
// Kernel 1 (fused h1+uv). R12 structure, but Hs ALIASED into As:
// LDS 51.2 KB -> 33.8 KB => 4 blocks/CU (was 3). Two extra barriers protect
// the alias (barriers measured ~free in R10). Timeline:
//   stage X->As | phase1 MFMA(As) | Hs=relu(acc1) into As[0..8703] |
//   phase2 MFMA(Hs) | acc2 -> As[64][264] | bulk store U||V
// ---------------------------------------------------------------------------
__global__ __launch_bounds__(256) void k_h1uv(
    const float* __restrict__ X, const __bf16* __restrict__ WtH,
    const __bf16* __restrict__ WtG2, const float* __restrict__ b,
    __bf16* __restrict__ U, __bf16* __restrict__ V)
{
    __shared__ __bf16 As[64 * 264];          // 33792 B, multi-purpose
    __bf16* Hs = As;                         // alias: [64][136] after phase 1

    const int tid  = threadIdx.x;
    const int row0 = blockIdx.x * 64;
    const int wave = tid >> 6, lane = tid & 63;
    const int lm = lane & 15, lq = lane >> 4;

    // B1 panel resident (64 VGPR)
    bf16x8 b1[2][8];
    #pragma unroll
    for (int nt = 0; nt < 2; ++nt) {
        int ntg = wave * 2 + nt;
        #pragma unroll
        for (int ks = 0; ks < 8; ++ks)
            b1[nt][ks] = *(const bf16x8*)(WtH + (size_t)(ntg * 16 + lm) * 256 + ks * 32 + lq * 8);
    }

    // bulk stage X: 64x256 fp32 -> bf16 (16 float4 loads/thread in flight)
    #pragma unroll
    for (int it = 0; it < 16; ++it) {
        int f4  = it * 256 + tid;
        int row = f4 >> 6, c4 = f4 & 63;
        int grow = row0 + row; if (grow >= L_NODES) grow = L_NODES - 1;
        float4 v = *(const float4*)(X + (size_t)grow * NFEAT + c4 * 4);
        bf16x4 o; o[0]=(__bf16)v.x; o[1]=(__bf16)v.y; o[2]=(__bf16)v.z; o[3]=(__bf16)v.w;
        *(bf16x4*)&As[row * 264 + c4 * 4] = o;
    }
    __syncthreads();

    // phase 1: H accs (wave = 4 m-tiles x 2 nt)
    floatx4 acc1[4][2] = {};
    #pragma unroll
    for (int ks = 0; ks < 8; ++ks) {
        bf16x8 af[4];
        #pragma unroll
        for (int t = 0; t < 4; ++t)
            af[t] = *(const bf16x8*)&As[(t * 16 + lm) * 264 + ks * 32 + lq * 8];
        #pragma unroll
        for (int t = 0; t < 4; ++t)
            #pragma unroll
            for (int nt = 0; nt < 2; ++nt)
                acc1[t][nt] = __builtin_amdgcn_mfma_f32_16x16x32_bf16(
                    af[t], b1[nt][ks], acc1[t][nt], 0, 0, 0);
    }
    __syncthreads();   // As (X tile) dead; safe to overwrite with Hs

    // B2 panel (loaded here, as in R12 — keeps VGPR ~80)
    bf16x8 b2[4][4];
    #pragma unroll
    for (int nt = 0; nt < 4; ++nt) {
        int ntg = wave * 4 + nt;
        #pragma unroll
        for (int ks = 0; ks < 4; ++ks)
            b2[nt][ks] = *(const bf16x8*)(WtG2 + (size_t)(ntg * 16 + lm) * 128 + ks * 32 + lq * 8);
    }

    // H (bias+relu) -> Hs (= As[0..8703], [64][136])
    #pragma unroll
    for (int nt = 0; nt < 2; ++nt) {
        int col = (wave * 2 + nt) * 16 + lm;
        float bias = b[col];
        #pragma unroll
        for (int t = 0; t < 4; ++t)
            #pragma unroll
            for (int p = 0; p < 4; ++p)
                Hs[(t * 16 + lq * 4 + p) * 136 + col] =
                    (__bf16)fmaxf(acc1[t][nt][p] + bias, 0.f);
    }
    __syncthreads();

    // phase 2: U||V accs (wave = 4 m-tiles x 4 nt over N=256), K=128 from Hs
    floatx4 acc2[4][4] = {};
    #pragma unroll
    for (int ks = 0; ks < 4; ++ks) {
        bf16x8 af[4];
        #pragma unroll
        for (int t = 0; t < 4; ++t)
            af[t] = *(const bf16x8*)&Hs[(t * 16 + lm) * 136 + ks * 32 + lq * 8];
        #pragma unroll
        for (int t = 0; t < 4; ++t)
            #pragma unroll
            for (int nt = 0; nt < 4; ++nt)
                acc2[t][nt] = __builtin_amdgcn_mfma_f32_16x16x32_bf16(
                    af[t], b2[nt][ks], acc2[t][nt], 0, 0, 0);
    }
    __syncthreads();   // Hs dead; safe to overwrite with output staging

    // acc2 -> As as [64][256] stride 264
    #pragma unroll
    for (int nt = 0; nt < 4; ++nt) {
        int col = (wave * 4 + nt) * 16 + lm;
        #pragma unroll
        for (int t = 0; t < 4; ++t)
            #pragma unroll
            for (int p = 0; p < 4; ++p)
                As[(t * 16 + lq * 4 + p) * 264 + col] = (__bf16)acc2[t][nt][p];
    }
    __syncthreads();

    // bulk store U (cols 0..127) / V (cols 128..255)
    #pragma unroll
    for (int it = 0; it < 8; ++it) {
        int fid = it * 256 + tid;
        int row = fid >> 5, c8 = fid & 31;
        int grow = row0 + row;
        if (grow < L_NODES) {
            int col = c8 * 8;
            bf16x8 v = *(bf16x8*)&As[row * 264 + col];
            if (col < 128) *(bf16x8*)(U + (size_t)grow * JDIM + col) = v;
            else           *(bf16x8*)(V + (size_t)grow * JDIM + (col - 128)) = v;
        }
    }
}

// ---------------------------------------------------------------------------
// Kernel 2 (FUSED gather + final) — R12-proven. E1 never touches HBM.
//   phase A: E1[r] = relu(mean_s relu(U[idx0[s,r]] + V[idx1[s,r]] + bg)) -> LDS
//   phase B: E2 = relu(U + E1 @ Wg_bot + bg); out = E2 @ Wf + bf
// ---------------------------------------------------------------------------
__global__ __launch_bounds__(256) void k_gfinal(
    const __bf16* __restrict__ U, const __bf16* __restrict__ V,
    const __bf16* __restrict__ WtGv, const float* __restrict__ bg,
    const float* __restrict__ Wf, const float* __restrict__ bf,
    const int* __restrict__ idx0, const int* __restrict__ idx1,
    float* __restrict__ out)
{
    __shared__ int    sidx0[8][64], sidx1[8][64];   // 4 KB
    __shared__ __bf16 E1s[64 * 136];                // 17.4 KB
    __shared__ __bf16 Us [64 * 136];                // 17.4 KB
    __shared__ float  part[4][64][2];               // 2 KB

    const int tid  = threadIdx.x;
    const int row0 = blockIdx.x * 64;
    const int wave = tid >> 6, lane = tid & 63;
    const int lm = lane & 15, lq = lane >> 4;

    // B panel resident: 8 frags = 32 VGPR
    bf16x8 b3[2][4];
    #pragma unroll
    for (int nt = 0; nt < 2; ++nt) {
        int ntg = wave * 2 + nt;
        #pragma unroll
        for (int ks = 0; ks < 4; ++ks)
            b3[nt][ks] = *(const bf16x8*)(WtGv + (size_t)(ntg * 16 + lm) * 128 + ks * 32 + lq * 8);
    }

    // stage indices (4/thread) and U tile (4 bf16x8/thread)
    #pragma unroll
    for (int it = 0; it < 4; ++it) {
        int fid = it * 256 + tid;
        int m = fid >> 9, rem = fid & 511;
        int s = rem >> 6, il = rem & 63;
        int gr = row0 + il; if (gr >= L_NODES) gr = L_NODES - 1;
        int val = (m ? idx1 : idx0)[(size_t)s * L_NODES + gr];
        if (m) sidx1[s][il] = val; else sidx0[s][il] = val;
    }
    #pragma unroll
    for (int it = 0; it < 4; ++it) {
        int fid = it * 256 + tid;
        int r = fid >> 4, c8 = fid & 15;
        int g = row0 + r; if (g >= L_NODES) g = L_NODES - 1;
        *(bf16x8*)&Us[r * 136 + c8 * 8] = *(const bf16x8*)(U + (size_t)g * JDIM + c8 * 8);
    }
    __syncthreads();

    // phase A: gather-add into E1s
    {
        const int c0 = (tid & 15) * 8;
        const int rb = tid >> 4;
        float bias[8];
        *(float4*)&bias[0] = *(const float4*)(bg + c0);
        *(float4*)&bias[4] = *(const float4*)(bg + c0 + 4);

        float acc[4][8] = {};
        #pragma unroll
        for (int s = 0; s < 8; ++s) {
            #pragma unroll
            for (int rr = 0; rr < 4; ++rr) {
                int r = rb + rr * 16;
                int a0 = sidx0[s][r], a1 = sidx1[s][r];
                bf16x8 u = *(const bf16x8*)(U + (size_t)a0 * JDIM + c0);
                bf16x8 v = *(const bf16x8*)(V + (size_t)a1 * JDIM + c0);
                #pragma unroll
                for (int p = 0; p < 8; ++p)
                    acc[rr][p] += fmaxf((float)u[p] + (float)v[p] + bias[p], 0.f);
            }
        }
        #pragma unroll
        for (int rr = 0; rr < 4; ++rr) {
            int r = rb + rr * 16;
            bf16x8 o;
            #pragma unroll
            for (int p = 0; p < 8; ++p)
                o[p] = (__bf16)fmaxf(acc[rr][p] * 0.125f, 0.f);
            *(bf16x8*)&E1s[r * 136 + c0] = o;
        }
    }
    __syncthreads();

    // phase B: E2 = relu(U + E1 @ Wg_bot + bg); head
    floatx4 acc[4][2] = {};
    #pragma unroll
    for (int ks = 0; ks < 4; ++ks) {
        bf16x8 af[4];
        #pragma unroll
        for (int t = 0; t < 4; ++t)
            af[t] = *(const bf16x8*)&E1s[(t * 16 + lm) * 136 + ks * 32 + lq * 8];
        #pragma unroll
        for (int t = 0; t < 4; ++t)
            #pragma unroll
            for (int nt = 0; nt < 2; ++nt)
                acc[t][nt] = __builtin_amdgcn_mfma_f32_16x16x32_bf16(
                    af[t], b3[nt][ks], acc[t][nt], 0, 0, 0);
    }

    float bias[2], wf0[2], wf1[2];
    #pragma unroll
    for (int nt = 0; nt < 2; ++nt) {
        int col = (wave * 2 + nt) * 16 + lm;
        bias[nt] = bg[col];
        wf0[nt] = Wf[col * 2 + 0];
        wf1[nt] = Wf[col * 2 + 1];
    }
    #pragma unroll
    for (int t = 0; t < 4; ++t) {
        float p0[4], p1[4];
        #pragma unroll
        for (int p = 0; p < 4; ++p) {
            int r = t * 16 + lq * 4 + p;
            float a0 = 0.f, a1 = 0.f;
            #pragma unroll
            for (int nt = 0; nt < 2; ++nt) {
                int col = (wave * 2 + nt) * 16 + lm;
                float e2 = fmaxf((float)Us[r * 136 + col] + acc[t][nt][p] + bias[nt], 0.f);
                a0 = fmaf(e2, wf0[nt], a0);
                a1 = fmaf(e2, wf1[nt], a1);
            }
            p0[p] = a0; p1[p] = a1;
        }
        #pragma unroll
        for (int m = 1; m <= 8; m <<= 1)
            #pragma unroll
            for (int p = 0; p < 4; ++p) {
                p0[p] += __shfl_xor(p0[p], m, 16);
                p1[p] += __shfl_xor(p1[p], m, 16);
            }
        if (lm == 0)
            #pragma unroll
            for (int p = 0; p < 4; ++p) {
                part[wave][t * 16 + lq * 4 + p][0] = p0[p];
                part[wave][t * 16 + lq * 4 + p][1] = p1[p];
            }
    }
    __syncthreads();

    if (tid < 128) {
        int row = tid >> 1, o = tid & 1;
        int grow = row0 + row;
        if (grow < L_NODES)
            out[(size_t)grow * 2 + o] =
                part[0][row][o] + part[1][row][o] + part[2][row][o] + part[3][row][o] + bf[o];
    }
}

// ---------------------------------------------------------------------------
extern "C" void kernel_launch(void* const* d_in, const int* in_sizes, int n_in,
                              void* d_out, int out_size, void* d_ws, size_t ws_size,
                              hipStream_t stream) {
    const float* X    = (const float*)d_in[0];
    const float* W_h1 = (const float*)d_in[1];
    const float* b_h1 = (const float*)d_in[2];
    const float* W_g1 = (const float*)d_in[3];
    const float* b_g1 = (const float*)d_in[4];
    const float* W_f  = (const float*)d_in[5];
    const float* b_f  = (const float*)d_in[6];
    const int*   idx0 = (const int*)d_in[7];
    const int*   idx1 = (const int*)d_in[8];
    float* out = (float*)d_out;

    __bf16* U    = (__bf16*)d_ws;                         // 25.6 MB
    __bf16* V    = U   + (size_t)L_NODES * JDIM;          // 25.6 MB
    __bf16* WtH  = V   + (size_t)L_NODES * JDIM;          // 64 KB
    __bf16* WtG2 = WtH + 32768;                           // 64 KB
    __bf16* WtGv = WtG2 + 128 * 128;                      // alias: rows 128.. of WtG2

    k_prep<<<128, 256, 0, stream>>>(W_h1, W_g1, WtH, WtG2);
    k_h1uv<<<(L_NODES + 63) / 64, 256, 0, stream>>>(X, WtH, WtG2, b_h1, U, V);
    k_gfinal<<<(L_NODES + 63) / 64, 256, 0, stream>>>(U, V, WtGv, b_g1, W_f, b_f,
                                                      idx0, idx1, out);
}